// Round 3
// baseline (203.628 us; speedup 1.0000x reference)
//
#include <hip/hip_runtime.h>

// Problem constants (from reference setup_inputs):
// b=16, c=64, l=8, h=56, w=56  ->  cl = 512, n = 56*56 = 3136
#define BATCH 16
#define CL    512
#define NSP   3136
#define N4    (NSP / 4)            // 784 float4 per (b,c) row

// ---- pass 1 geometry: final-g, no cross-block channel partials ----
// block = 256 thr = 8 i4-lanes x 32 channel-groups (16 ch each)
#define ILANES 8
#define NGRP   32
#define CPG    (CL / NGRP)         // 16 channels per group
#define NCHUNK (N4 / ILANES)       // 98 chunks (exact: 784 = 98*8)

// ---- pass 2 geometry: one block = one (b, 16-channel slab) ----
#define ROWS_PB 16
#define P2_BLOCKS (BATCH * CL / ROWS_PB)        // 512
#define F4_PB   (ROWS_PB * N4)                  // 12544 = 49 * 256 exact

typedef float nfloat4 __attribute__((ext_vector_type(4)));

// ---------------------------------------------------------------------------
// Pass 1: g[b,i] = sum_c x[b,c,i]*g_w[c]          (FINAL, no partials)
//         t_part[b,chunk] = sum_{i in chunk} sum_c x[b,c,i]*theta_w[c]
// Grid (98, 16) = 1568 blocks (~6/CU, ~24 waves/CU).
// Wave load = 8 i4-lanes x 16B = 128B segments x 8 channels -> full lines.
// ---------------------------------------------------------------------------
__global__ __launch_bounds__(256) void sa_pass1(
    const float* __restrict__ x,        // [BATCH, CL, NSP]
    const float* __restrict__ theta_w,  // [CL]
    const float* __restrict__ g_w,      // [CL]
    float* __restrict__ g_out,          // ws: [BATCH][N4] float4
    float* __restrict__ t_part)         // ws: [BATCH][NCHUNK]
{
    const int chunk = blockIdx.x;        // 0..97
    const int b     = blockIdx.y;        // 0..15
    const int tid   = threadIdx.x;
    const int il    = tid & (ILANES - 1);     // i4 lane 0..7
    const int grp   = tid >> 3;               // channel group 0..31
    const int i4    = chunk * ILANES + il;    // < 784 always (exact tiling)
    const int c0    = grp * CPG;

    const float4* xb = (const float4*)x + ((size_t)b * CL + c0) * N4 + i4;

    float4 gv = make_float4(0.f, 0.f, 0.f, 0.f);
    float4 tv = make_float4(0.f, 0.f, 0.f, 0.f);
    #pragma unroll
    for (int k = 0; k < CPG; ++k) {          // 16 independent loads in flight
        float4 xv = xb[(size_t)k * N4];
        const float gw = g_w[c0 + k];        // wave-uniform -> scalar load
        const float tw = theta_w[c0 + k];
        gv.x += xv.x * gw; gv.y += xv.y * gw;
        gv.z += xv.z * gw; gv.w += xv.w * gw;
        tv.x += xv.x * tw; tv.y += xv.y * tw;
        tv.z += xv.z * tw; tv.w += xv.w * tw;
    }

    __shared__ float4 sg[NGRP][ILANES];      // 4 KB
    __shared__ float  st[NGRP][ILANES];      // 1 KB
    sg[grp][il] = gv;
    st[grp][il] = tv.x + tv.y + tv.z + tv.w;
    __syncthreads();

    if (tid < 64) {
        // lane layout: i = tid&7, h = tid>>3 (8 group-slots); each slot
        // sums 4 of the 32 groups, then shfl-tree over h, then over i for t.
        const int i = tid & 7;
        const int h = tid >> 3;
        float4 G = sg[h][i];
        float  T = st[h][i];
        #pragma unroll
        for (int j = 1; j < 4; ++j) {
            float4 a = sg[h + 8 * j][i];
            G.x += a.x; G.y += a.y; G.z += a.z; G.w += a.w;
            T += st[h + 8 * j][i];
        }
        #pragma unroll
        for (int off = 32; off >= 8; off >>= 1) {   // reduce over h (x8)
            G.x += __shfl_down(G.x, off);
            G.y += __shfl_down(G.y, off);
            G.z += __shfl_down(G.z, off);
            G.w += __shfl_down(G.w, off);
            T   += __shfl_down(T, off);
        }
        if (tid < 8)    // h==0 lanes hold the full channel sum for i4 = base+i
            ((float4*)g_out)[(size_t)b * N4 + chunk * ILANES + tid] = G;
        #pragma unroll
        for (int off = 4; off > 0; off >>= 1)       // reduce T over i
            T += __shfl_down(T, off);
        if (tid == 0)
            t_part[b * NCHUNK + chunk] = T;
    }
}

// ---------------------------------------------------------------------------
// Pass 2: out[b,c,i] = x[b,c,i] + m[b]*g[b,i]*h_w[c] + h_b[c]
// Block = one (b, 16-row channel slab): 12544 float4 = 49 exact iterations.
// Prologue stages g[784] -> LDS (once per block, replaces per-element L2
// loads), h_w/h_b slab -> LDS, and wave 0 reduces the 98 t-partials -> m.
// Grid 512 blocks (2/CU, 8 waves/CU; 49-deep per-thread MLP hides latency).
// x re-read hits L3 (98 MiB, warmed by pass1). Nontemporal store of out.
// ---------------------------------------------------------------------------
__global__ __launch_bounds__(256) void sa_pass2(
    const float* __restrict__ x,
    const float* __restrict__ g_arr,   // [BATCH][N4] float4
    const float* __restrict__ t_part,  // [BATCH][NCHUNK]
    const float* __restrict__ h_w,     // [CL]
    const float* __restrict__ h_b,     // [CL]
    float* __restrict__ out)
{
    const int blk = blockIdx.x;          // 0..511
    const int b   = blk >> 5;            // 16 slabs... blk / 32
    const int c0  = (blk & 31) * ROWS_PB;
    const int tid = threadIdx.x;

    __shared__ float4 sgl[N4];           // 12544 B combined g for this batch
    __shared__ float  shw[ROWS_PB];
    __shared__ float  shb[ROWS_PB];
    __shared__ float  sm;

    const float4* gsrc = (const float4*)g_arr + (size_t)b * N4;
    #pragma unroll
    for (int l = tid; l < N4; l += 256)          // 3-4 iters
        sgl[l] = gsrc[l];
    if (tid < ROWS_PB) {
        shw[tid] = h_w[c0 + tid];
        shb[tid] = h_b[c0 + tid];
    }
    if (tid < 64) {                               // reduce 98 t-partials
        const float* tp = t_part + b * NCHUNK;
        float v = tp[tid] + ((tid < NCHUNK - 64) ? tp[tid + 64] : 0.f);
        #pragma unroll
        for (int off = 32; off > 0; off >>= 1)
            v += __shfl_down(v, off);
        if (tid == 0)
            sm = v * (1.0f / (float)NSP);
    }
    __syncthreads();
    const float m = sm;

    const size_t base = ((size_t)b * CL + c0) * N4;    // block's first float4
    #pragma unroll 7
    for (int r = 0; r < F4_PB / 256; ++r) {            // 49 exact iterations
        const int l  = r * 256 + tid;                  // 0..12543
        const int cl = l / N4;                         // magic-mul division
        const int i4 = l - cl * N4;

        float4 xv = ((const float4*)x)[base + l];      // L3 hit (pass1-warmed)
        float4 gv = sgl[i4];                           // LDS broadcast-ish
        const float mh = m * shw[cl];
        const float hb = shb[cl];

        nfloat4 o;
        o.x = xv.x + mh * gv.x + hb;
        o.y = xv.y + mh * gv.y + hb;
        o.z = xv.z + mh * gv.z + hb;
        o.w = xv.w + mh * gv.w + hb;
        // Nontemporal: out is never re-read; keep x resident in L2/L3.
        __builtin_nontemporal_store(o, (nfloat4*)out + base + l);
    }
}

extern "C" void kernel_launch(void* const* d_in, const int* in_sizes, int n_in,
                              void* d_out, int out_size, void* d_ws, size_t ws_size,
                              hipStream_t stream)
{
    const float* x       = (const float*)d_in[0];
    const float* theta_w = (const float*)d_in[1];
    const float* g_w     = (const float*)d_in[2];
    const float* h_w     = (const float*)d_in[3];
    const float* h_b     = (const float*)d_in[4];
    float* out = (float*)d_out;

    // Workspace layout (every byte written by pass1 before pass2 reads it):
    //   [0,      200704) : g_ws  (16*784 float4 = 196 KiB)
    //   [200704, 206976) : t_ws  (16*98 floats = 6272 B)
    char* ws = (char*)d_ws;
    float* g_ws = (float*)ws;
    float* t_ws = (float*)(ws + (size_t)BATCH * N4 * 16);

    dim3 grid1(NCHUNK, BATCH);   // (98, 16) = 1568 blocks
    sa_pass1<<<grid1, 256, 0, stream>>>(x, theta_w, g_w, g_ws, t_ws);

    sa_pass2<<<P2_BLOCKS, 256, 0, stream>>>(x, g_ws, t_ws, h_w, h_b, out);
}